// Round 10
// baseline (1211.294 us; speedup 1.0000x reference)
//
#include <hip/hip_runtime.h>

#define TT 512

typedef _Float16 f16;
typedef _Float16 f16x4 __attribute__((ext_vector_type(4)));
typedef _Float16 f16x8 __attribute__((ext_vector_type(8)));
typedef float    f32x4 __attribute__((ext_vector_type(4)));

#define MFMA(A, B, C) __builtin_amdgcn_mfma_f32_16x16x32_f16((A), (B), (C), 0, 0, 0)

#define LOG2E  1.44269504f
#define LOG2E2 2.88539008f

__device__ __forceinline__ float exp2_(float x){
#if __has_builtin(__builtin_amdgcn_exp2f)
    return __builtin_amdgcn_exp2f(x);
#else
    return exp2f(x);
#endif
}
__device__ __forceinline__ float rcp_(float x){
#if __has_builtin(__builtin_amdgcn_rcpf)
    return __builtin_amdgcn_rcpf(x);
#else
    return 1.0f/x;
#endif
}
__device__ __forceinline__ f16x8 ldw8s(const float* p, float s){
    f16x8 r;
    #pragma unroll
    for (int i = 0; i < 8; ++i) r[i] = (f16)(p[i]*s);
    return r;
}

// Gate pre-scaling: i/f/o rows by LOG2E, g rows by LOG2E2 (folded into W+b).
// Shared-rcp: sig(a)*tanh(b) = (1-Eb)/((1+Ea)(1+Eb)).
__device__ __forceinline__ void act4(const f32x4& zi, const f32x4& zf,
                                     const f32x4& zg, const f32x4& zo,
                                     f32x4& c, f16x4& hn){
    #pragma unroll
    for (int j = 0; j < 4; ++j){
        float Ef = exp2_(-zf[j]);
        float Ei = exp2_(-zi[j]);
        float Eg = exp2_(-zg[j]);
        float Eo = exp2_(-zo[j]);
        float f_ = rcp_(1.0f + Ef);
        float ig = (1.0f - Eg) * rcp_((1.0f + Ei)*(1.0f + Eg));
        c[j] = fmaf(f_, c[j], ig);
        float Ec = exp2_(-(LOG2E2*c[j]));
        float h_ = (1.0f - Ec) * rcp_((1.0f + Eo)*(1.0f + Ec));
        hn[j] = (f16)h_;
    }
}

#define LDS_FENCE() __asm__ volatile("s_waitcnt lgkmcnt(0)" ::: "memory")
#define MEMBAR()    __asm__ volatile("" ::: "memory")

// Counters: [0]=A1 [1]=A2 [2]=A3 [4]=C1 [5]=C2 [6]=C3 (arrive / consumed, cumulative).
// 64 blocks x 256 threads (4 waves, 1/SIMD, up to 512 VGPR each).
// wave0=L1, wave1=L2, wave2=L3, wave3=FC. Batch 16 per block.
// Each L-wave owns its ENTIRE layer: weights as 64 f16x8 A-frags in VGPRs.
// h rings (LDS): ring[l][slot=t&3][16b][64u] f16, XOR-swizzled rows. A wave's own
// recurrence reads its own ring slot (same-wave DS ops are ordered -> NO sync);
// only the forward hops L1->L2->L3->FC use arrive/consumed flags (4-deep rings).
__global__ __launch_bounds__(256, 1) void lstm3_selfwave(
    const float* __restrict__ x,
    const float* __restrict__ w_ih1, const float* __restrict__ w_hh1, const float* __restrict__ b1,
    const float* __restrict__ w_ih2, const float* __restrict__ w_hh2, const float* __restrict__ b2,
    const float* __restrict__ w_ih3, const float* __restrict__ w_hh3, const float* __restrict__ b3,
    const float* __restrict__ fc1_w, const float* __restrict__ fc1_b,
    const float* __restrict__ fc2_w, const float* __restrict__ fc2_b,
    float* __restrict__ out)
{
    __shared__ __align__(16) unsigned char hring[3*4*2048];  // [layer][slot][16b][64u] f16
    __shared__ float x_lds[TT*17];                           // [t][batch]
    __shared__ int cnt[8];

    const int tid = threadIdx.x;
    const int wid = tid >> 6;
    const int l   = tid & 63;
    const int q   = l >> 4;
    const int bb  = l & 15;
    const int b0  = blockIdx.x * 16;

    for (int i = tid; i < 16*TT; i += 256){
        int b = i >> 9, t = i & (TT-1);
        x_lds[t*17 + b] = x[(size_t)(b0+b)*TT + t];
    }
    for (int i = tid; i < (int)sizeof(hring)/4; i += 256)
        ((unsigned int*)hring)[i] = 0u;
    if (tid < 8) cnt[tid] = 0;

    // t-invariant LDS byte offsets within a 2 KB slot (16 rows x 128 B, swizzled)
    const int rowb = bb*128;
    const int swz  = 16*(bb&7);
    const int rdA  = rowb + ((16*q     ) ^ swz);
    const int rdB  = rowb + ((16*q + 64) ^ swz);
    int wrm[4];
    #pragma unroll
    for (int m = 0; m < 4; ++m) wrm[m] = rowb + ((32*m + 8*q) ^ swz);  // units 16m+4q..+3

    const f32x4 vzero = {0.f, 0.f, 0.f, 0.f};

    if (wid == 3){
        // ---------------- FC wave ----------------
        f16x8 wfc[2][2];
        f32x4 fb4[2], fw4[2];
        #pragma unroll
        for (int rt = 0; rt < 2; ++rt){
            #pragma unroll
            for (int kt = 0; kt < 2; ++kt)
                wfc[rt][kt] = ldw8s(fc1_w + (16*rt + bb)*64 + kt*32 + q*8, 1.0f);
            #pragma unroll
            for (int j = 0; j < 4; ++j){
                fb4[rt][j] = fc1_b[16*rt + 4*q + j];
                fw4[rt][j] = fc2_w[16*rt + 4*q + j];
            }
        }
        const float fc2bs = fc2_b[0];
        float obuf0 = 0.f, obuf1 = 0.f, obuf2 = 0.f;
        __syncthreads();
        #pragma unroll 1
        for (int t = 0; t < TT; ++t){
            { volatile int* vp = (volatile int*)cnt;
              while (vp[2] < t+1) {} }                       // A3: h3(t) ready
            MEMBAR();
            const unsigned char* s3 = hring + 2*8192 + (t&3)*2048;
            const f16x8 pA = *(const f16x8*)(s3 + rdA);
            const f16x8 pB = *(const f16x8*)(s3 + rdB);
            LDS_FENCE();
            if (l == 1) atomicAdd(&cnt[6], 1);               // C3
            f32x4 y0 = MFMA(wfc[0][0], pA, fb4[0]); y0 = MFMA(wfc[0][1], pB, y0);
            f32x4 y1 = MFMA(wfc[1][0], pA, fb4[1]); y1 = MFMA(wfc[1][1], pB, y1);
            float s = 0.f;
            #pragma unroll
            for (int j = 0; j < 4; ++j){
                float u0 = fmaxf(y0[j], 0.2f*y0[j]);         // leaky_relu(0.2)
                s = fmaf(u0, fw4[0][j], s);
                float u1 = fmaxf(y1[j], 0.2f*y1[j]);
                s = fmaf(u1, fw4[1][j], s);
            }
            s += __shfl_xor(s, 16);
            s += __shfl_xor(s, 32);
            s += fc2bs;
            const int ph = t & 3;
            if (ph == 0) obuf0 = s;
            else if (ph == 1) obuf1 = s;
            else if (ph == 2) obuf2 = s;
            else if (l < 16){
                float4 v4 = make_float4(obuf0, obuf1, obuf2, s);
                *(float4*)(out + (size_t)(b0+l)*TT + (t - 3)) = v4;
            }
        }
        return;
    }

    // ---------------- LSTM layer waves (wid 0,1,2) ----------------
    const int L = wid;                                       // layer index
    const float* Wih = (L == 1) ? w_ih2 : w_ih3;             // unused for L0
    const float* Whh = (L == 0) ? w_hh1 : (L == 1 ? w_hh2 : w_hh3);
    const float* bp  = (L == 0) ? b1   : (L == 1 ? b2    : b3);

    // full-layer weights: frag [m][g][kt], row-tile rt = 4g+m, rows 16rt+bb
    f16x8 wHH[4][4][2], wIH[4][4][2];
    f32x4 b4[4][4], wx4[4][4];
    #pragma unroll
    for (int g = 0; g < 4; ++g){
        const float sg = (g == 2) ? LOG2E2 : LOG2E;
        #pragma unroll
        for (int m = 0; m < 4; ++m){
            const int rowbase = (64*g + 16*m + bb)*64;
            #pragma unroll
            for (int kt = 0; kt < 2; ++kt){
                wHH[m][g][kt] = ldw8s(Whh + rowbase + kt*32 + q*8, sg);
                if (L != 0) wIH[m][g][kt] = ldw8s(Wih + rowbase + kt*32 + q*8, sg);
            }
            #pragma unroll
            for (int j = 0; j < 4; ++j){
                const int r = 64*g + 16*m + 4*q + j;
                b4[m][g][j] = bp[r]*sg;
                if (L == 0) wx4[m][g][j] = w_ih1[r]*sg;
            }
        }
    }

    f32x4 c4[4] = {vzero, vzero, vzero, vzero};
    unsigned char* ringo = hring + L*8192;                   // own ring
    const unsigned char* ringi = hring + (L-1)*8192;         // input ring (L>=1)

    __syncthreads();

    #pragma unroll 1
    for (int t = 0; t < TT; ++t){
        // ---- poll: input arrive (L>=1) + own-ring free (downstream consumed) ----
        if (L == 0){
            volatile int* vp = (volatile int*)cnt;
            while (vp[4] < t-3) {}                           // C1
        } else if (L == 1){
            volatile int* vp = (volatile int*)cnt;
            while (vp[0] < t+1 || vp[5] < t-3) {}            // A1, C2
        } else {
            volatile int* vp = (volatile int*)cnt;
            while (vp[1] < t+1 || vp[6] < t-3) {}            // A2, C3
        }
        MEMBAR();

        const unsigned char* self_s = ringo + ((t-1)&3)*2048;
        unsigned char*       wr_s   = ringo + ((t  )&3)*2048;
        const f16x8 hA = *(const f16x8*)(self_s + rdA);
        const f16x8 hB = *(const f16x8*)(self_s + rdB);
        f16x8 iA, iB;
        float xv = 0.f;
        if (L == 0){
            xv = x_lds[t*17 + bb];
        } else {
            const unsigned char* in_s = ringi + (t&3)*2048;
            iA = *(const f16x8*)(in_s + rdA);
            iB = *(const f16x8*)(in_s + rdB);
            LDS_FENCE();
            if (l == 1) atomicAdd(&cnt[3 + L], 1);           // C1/C2 consumed-input
        }

        #pragma unroll
        for (int m = 0; m < 4; ++m){
            f32x4 zi, zf, zg, zo;
            if (L == 0){
                #pragma unroll
                for (int j = 0; j < 4; ++j){
                    zi[j] = fmaf(wx4[m][0][j], xv, b4[m][0][j]);
                    zf[j] = fmaf(wx4[m][1][j], xv, b4[m][1][j]);
                    zg[j] = fmaf(wx4[m][2][j], xv, b4[m][2][j]);
                    zo[j] = fmaf(wx4[m][3][j], xv, b4[m][3][j]);
                }
            } else {
                zi = MFMA(wIH[m][0][0], iA, b4[m][0]); zi = MFMA(wIH[m][0][1], iB, zi);
                zf = MFMA(wIH[m][1][0], iA, b4[m][1]); zf = MFMA(wIH[m][1][1], iB, zf);
                zg = MFMA(wIH[m][2][0], iA, b4[m][2]); zg = MFMA(wIH[m][2][1], iB, zg);
                zo = MFMA(wIH[m][3][0], iA, b4[m][3]); zo = MFMA(wIH[m][3][1], iB, zo);
            }
            zi = MFMA(wHH[m][0][0], hA, zi); zi = MFMA(wHH[m][0][1], hB, zi);
            zf = MFMA(wHH[m][1][0], hA, zf); zf = MFMA(wHH[m][1][1], hB, zf);
            zg = MFMA(wHH[m][2][0], hA, zg); zg = MFMA(wHH[m][2][1], hB, zg);
            zo = MFMA(wHH[m][3][0], hA, zo); zo = MFMA(wHH[m][3][1], hB, zo);
            f16x4 hn;
            act4(zi, zf, zg, zo, c4[m], hn);
            *(f16x4*)(wr_s + wrm[m]) = hn;                   // units 16m+4q..+3, batch bb
        }
        LDS_FENCE();
        if (l == 0) atomicAdd(&cnt[L], 1);                   // A1/A2/A3 arrive
    }
}

extern "C" void kernel_launch(void* const* d_in, const int* in_sizes, int n_in,
                              void* d_out, int out_size, void* d_ws, size_t ws_size,
                              hipStream_t stream)
{
    (void)in_sizes; (void)n_in; (void)d_ws; (void)ws_size; (void)out_size;
    const float* x     = (const float*)d_in[0];
    const float* w_ih1 = (const float*)d_in[1];
    const float* w_hh1 = (const float*)d_in[2];
    const float* b1    = (const float*)d_in[3];
    const float* w_ih2 = (const float*)d_in[4];
    const float* w_hh2 = (const float*)d_in[5];
    const float* b2    = (const float*)d_in[6];
    const float* w_ih3 = (const float*)d_in[7];
    const float* w_hh3 = (const float*)d_in[8];
    const float* b3    = (const float*)d_in[9];
    const float* fc1_w = (const float*)d_in[10];
    const float* fc1_b = (const float*)d_in[11];
    const float* fc2_w = (const float*)d_in[12];
    const float* fc2_b = (const float*)d_in[13];

    lstm3_selfwave<<<dim3(64), dim3(256), 0, stream>>>(
        x, w_ih1, w_hh1, b1, w_ih2, w_hh2, b2, w_ih3, w_hh3, b3,
        fc1_w, fc1_b, fc2_w, fc2_b, (float*)d_out);
}

// Round 11
// 857.981 us; speedup vs baseline: 1.4118x; 1.4118x over previous
//
#include <hip/hip_runtime.h>

#define TT 512
#define KK 8
#define NPH (TT/KK + 3)   // 67 phases

typedef _Float16 f16;
typedef _Float16 f16x4 __attribute__((ext_vector_type(4)));
typedef _Float16 f16x8 __attribute__((ext_vector_type(8)));
typedef float    f32x4 __attribute__((ext_vector_type(4)));

#define MFMA(A, B, C) __builtin_amdgcn_mfma_f32_16x16x32_f16((A), (B), (C), 0, 0, 0)

#define LOG2E  1.44269504f
#define LOG2E2 2.88539008f

__device__ __forceinline__ float exp2_(float x){
#if __has_builtin(__builtin_amdgcn_exp2f)
    return __builtin_amdgcn_exp2f(x);
#else
    return exp2f(x);
#endif
}
__device__ __forceinline__ float rcp_(float x){
#if __has_builtin(__builtin_amdgcn_rcpf)
    return __builtin_amdgcn_rcpf(x);
#else
    return 1.0f/x;
#endif
}
__device__ __forceinline__ f16x8 ldw8s(const float* p, float s){
    f16x8 r;
    #pragma unroll
    for (int i = 0; i < 8; ++i) r[i] = (f16)(p[i]*s);
    return r;
}

// Gate pre-scaling: i/f/o rows by LOG2E, g rows by LOG2E2 (folded into W+b).
// Shared-rcp: sig(a)*tanh(b) = (1-Eb)/((1+Ea)(1+Eb)).
__device__ __forceinline__ void act4(const f32x4& zi, const f32x4& zf,
                                     const f32x4& zg, const f32x4& zo,
                                     f32x4& c, f16x4& hn){
    #pragma unroll
    for (int j = 0; j < 4; ++j){
        float Ef = exp2_(-zf[j]);
        float Ei = exp2_(-zi[j]);
        float Eg = exp2_(-zg[j]);
        float Eo = exp2_(-zo[j]);
        float f_ = rcp_(1.0f + Ef);
        float ig = (1.0f - Eg) * rcp_((1.0f + Ei)*(1.0f + Eg));
        c[j] = fmaf(f_, c[j], ig);
        float Ec = exp2_(-(LOG2E2*c[j]));
        float h_ = (1.0f - Ec) * rcp_((1.0f + Eo)*(1.0f + Ec));
        hn[j] = (f16)h_;
    }
}

// 256 blocks x 256 threads (4 waves, 1 wave/SIMD -> 512-reg budget), batch 4.
// w0=L1, w1=L2, w2=L3, w3=FC. Each L-wave owns its WHOLE layer (weights in reg).
// Self-recurrence: wave-private LDS ring (same-wave DS ordering -> no sync).
// Inter-layer: K=8-step phases, ONE __syncthreads per phase; 16-slot rings give
// disjoint read/write windows (mod 16) between adjacent pipeline stages.
// Phase p: L1 computes t in [8p,8p+8), L2 [8p-8,..), L3 [8p-16,..), FC [8p-24,..).
__global__ __launch_bounds__(256, 1) void lstm3_kwave(
    const float* __restrict__ x,
    const float* __restrict__ w_ih1, const float* __restrict__ w_hh1, const float* __restrict__ b1,
    const float* __restrict__ w_ih2, const float* __restrict__ w_hh2, const float* __restrict__ b2,
    const float* __restrict__ w_ih3, const float* __restrict__ w_hh3, const float* __restrict__ b3,
    const float* __restrict__ fc1_w, const float* __restrict__ fc1_b,
    const float* __restrict__ fc2_w, const float* __restrict__ fc2_b,
    float* __restrict__ out)
{
    __shared__ __align__(16) unsigned char hring[3*16*2048];  // [layer][slot16][16r x 128B]
    __shared__ float x_lds[TT*5];                             // [t][b4] stride 5

    const int tid = threadIdx.x;
    const int wid = tid >> 6;
    const int l   = tid & 63;
    const int q   = l >> 4;
    const int bb  = l & 15;
    const int b0  = blockIdx.x * 4;

    for (int i = tid; i < 4*TT; i += 256){
        int b = i >> 9, t = i & (TT-1);
        x_lds[t*5 + b] = x[(size_t)(b0+b)*TT + t];
    }
    for (int i = tid; i < (int)sizeof(hring)/4; i += 256)
        ((unsigned int*)hring)[i] = 0u;

    // t-invariant LDS byte offsets (R1-verified swizzle; 2KB slots, rows 4-15 junk-parallel)
    const int rowb = bb*128;
    const int swz  = 16*(bb&7);
    const int rdA  = rowb + ((16*q     ) ^ swz);
    const int rdB  = rowb + ((16*q + 64) ^ swz);
    int wrm[4];
    #pragma unroll
    for (int m = 0; m < 4; ++m) wrm[m] = rowb + ((32*m + 8*q) ^ swz);

    const f32x4 vzero = {0.f, 0.f, 0.f, 0.f};

    __syncthreads();   // LDS init done; each role below hits NPH barriers

    if (wid == 0){
        // ================= L1 wave =================
        f16x8 wHH[4][4][2];
        f32x4 b4v[4][4], wx4[4][4];
        #pragma unroll
        for (int g = 0; g < 4; ++g){
            const float sg = (g == 2) ? LOG2E2 : LOG2E;
            #pragma unroll
            for (int m = 0; m < 4; ++m){
                const int rb_ = (64*g + 16*m + bb)*64;
                #pragma unroll
                for (int kt = 0; kt < 2; ++kt)
                    wHH[m][g][kt] = ldw8s(w_hh1 + rb_ + kt*32 + q*8, sg);
                #pragma unroll
                for (int j = 0; j < 4; ++j){
                    const int r = 64*g + 16*m + 4*q + j;
                    b4v[m][g][j] = b1[r]*sg;
                    wx4[m][g][j] = w_ih1[r]*sg;
                }
            }
        }
        f32x4 c4[4] = {vzero, vzero, vzero, vzero};
        #pragma unroll 1
        for (int p = 0; p < NPH; ++p){
            #pragma unroll
            for (int k = 0; k < KK; ++k){
                const int t = p*KK + k;
                if (t < TT){
                    const unsigned char* hs = hring + ((t-1)&15)*2048;
                    unsigned char*       ws = hring + ((t  )&15)*2048;
                    const f16x8 hA = *(const f16x8*)(hs + rdA);
                    const f16x8 hB = *(const f16x8*)(hs + rdB);
                    const float xv = x_lds[t*5 + (bb&3)];
                    #pragma unroll
                    for (int m = 0; m < 4; ++m){
                        f32x4 zi, zf, zg, zo;
                        #pragma unroll
                        for (int j = 0; j < 4; ++j){
                            zi[j] = fmaf(wx4[m][0][j], xv, b4v[m][0][j]);
                            zf[j] = fmaf(wx4[m][1][j], xv, b4v[m][1][j]);
                            zg[j] = fmaf(wx4[m][2][j], xv, b4v[m][2][j]);
                            zo[j] = fmaf(wx4[m][3][j], xv, b4v[m][3][j]);
                        }
                        zi = MFMA(wHH[m][0][0], hA, zi); zi = MFMA(wHH[m][0][1], hB, zi);
                        zf = MFMA(wHH[m][1][0], hA, zf); zf = MFMA(wHH[m][1][1], hB, zf);
                        zg = MFMA(wHH[m][2][0], hA, zg); zg = MFMA(wHH[m][2][1], hB, zg);
                        zo = MFMA(wHH[m][3][0], hA, zo); zo = MFMA(wHH[m][3][1], hB, zo);
                        f16x4 hn;
                        act4(zi, zf, zg, zo, c4[m], hn);
                        *(f16x4*)(ws + wrm[m]) = hn;
                    }
                }
            }
            __syncthreads();
        }
    } else if (wid < 3){
        // ================= L2 / L3 wave =================
        const float* Wih = (wid == 1) ? w_ih2 : w_ih3;
        const float* Whh = (wid == 1) ? w_hh2 : w_hh3;
        const float* bp  = (wid == 1) ? b2    : b3;
        unsigned char* ringI = hring + (wid-1)*32768;
        unsigned char* ringO = hring + (wid  )*32768;
        const int toff = wid * KK;

        f16x8 wIH[4][4][2], wHH[4][4][2];
        f32x4 b4v[4][4];
        #pragma unroll
        for (int g = 0; g < 4; ++g){
            const float sg = (g == 2) ? LOG2E2 : LOG2E;
            #pragma unroll
            for (int m = 0; m < 4; ++m){
                const int rb_ = (64*g + 16*m + bb)*64;
                #pragma unroll
                for (int kt = 0; kt < 2; ++kt){
                    wIH[m][g][kt] = ldw8s(Wih + rb_ + kt*32 + q*8, sg);
                    wHH[m][g][kt] = ldw8s(Whh + rb_ + kt*32 + q*8, sg);
                }
                #pragma unroll
                for (int j = 0; j < 4; ++j)
                    b4v[m][g][j] = bp[64*g + 16*m + 4*q + j]*sg;
            }
        }
        f32x4 c4[4] = {vzero, vzero, vzero, vzero};
        #pragma unroll 1
        for (int p = 0; p < NPH; ++p){
            #pragma unroll
            for (int k = 0; k < KK; ++k){
                const int t = p*KK + k - toff;
                if ((unsigned)t < TT){
                    const unsigned char* is = ringI + ((t  )&15)*2048;
                    const unsigned char* hs = ringO + ((t-1)&15)*2048;
                    unsigned char*       ws = ringO + ((t  )&15)*2048;
                    const f16x8 iA = *(const f16x8*)(is + rdA);
                    const f16x8 iB = *(const f16x8*)(is + rdB);
                    const f16x8 hA = *(const f16x8*)(hs + rdA);
                    const f16x8 hB = *(const f16x8*)(hs + rdB);
                    #pragma unroll
                    for (int m = 0; m < 4; ++m){
                        f32x4 zi, zf, zg, zo;
                        zi = MFMA(wIH[m][0][0], iA, b4v[m][0]); zi = MFMA(wIH[m][0][1], iB, zi);
                        zf = MFMA(wIH[m][1][0], iA, b4v[m][1]); zf = MFMA(wIH[m][1][1], iB, zf);
                        zg = MFMA(wIH[m][2][0], iA, b4v[m][2]); zg = MFMA(wIH[m][2][1], iB, zg);
                        zo = MFMA(wIH[m][3][0], iA, b4v[m][3]); zo = MFMA(wIH[m][3][1], iB, zo);
                        zi = MFMA(wHH[m][0][0], hA, zi); zi = MFMA(wHH[m][0][1], hB, zi);
                        zf = MFMA(wHH[m][1][0], hA, zf); zf = MFMA(wHH[m][1][1], hB, zf);
                        zg = MFMA(wHH[m][2][0], hA, zg); zg = MFMA(wHH[m][2][1], hB, zg);
                        zo = MFMA(wHH[m][3][0], hA, zo); zo = MFMA(wHH[m][3][1], hB, zo);
                        f16x4 hn;
                        act4(zi, zf, zg, zo, c4[m], hn);
                        *(f16x4*)(ws + wrm[m]) = hn;
                    }
                }
            }
            __syncthreads();
        }
    } else {
        // ================= FC wave =================
        f16x8 wfc[2][2];
        f32x4 fb4[2], fw4[2];
        #pragma unroll
        for (int rt = 0; rt < 2; ++rt){
            #pragma unroll
            for (int kt = 0; kt < 2; ++kt)
                wfc[rt][kt] = ldw8s(fc1_w + (16*rt + bb)*64 + kt*32 + q*8, 1.0f);
            #pragma unroll
            for (int j = 0; j < 4; ++j){
                fb4[rt][j] = fc1_b[16*rt + 4*q + j];
                fw4[rt][j] = fc2_w[16*rt + 4*q + j];
            }
        }
        const float fc2bs = fc2_b[0];
        float ob0 = 0.f, ob1 = 0.f, ob2 = 0.f;
        #pragma unroll 1
        for (int p = 0; p < NPH; ++p){
            #pragma unroll
            for (int k = 0; k < KK; ++k){
                const int t = p*KK + k - 3*KK;
                if ((unsigned)t < TT){
                    const unsigned char* s3 = hring + 2*32768 + (t&15)*2048;
                    const f16x8 pA = *(const f16x8*)(s3 + rdA);
                    const f16x8 pB = *(const f16x8*)(s3 + rdB);
                    f32x4 y0 = MFMA(wfc[0][0], pA, fb4[0]); y0 = MFMA(wfc[0][1], pB, y0);
                    f32x4 y1 = MFMA(wfc[1][0], pA, fb4[1]); y1 = MFMA(wfc[1][1], pB, y1);
                    float s = 0.f;
                    #pragma unroll
                    for (int j = 0; j < 4; ++j){
                        float u0 = fmaxf(y0[j], 0.2f*y0[j]);   // leaky_relu(0.2)
                        s = fmaf(u0, fw4[0][j], s);
                        float u1 = fmaxf(y1[j], 0.2f*y1[j]);
                        s = fmaf(u1, fw4[1][j], s);
                    }
                    s += __shfl_xor(s, 16);
                    s += __shfl_xor(s, 32);
                    s += fc2bs;
                    const int ph = t & 3;
                    if (ph == 0) ob0 = s;
                    else if (ph == 1) ob1 = s;
                    else if (ph == 2) ob2 = s;
                    else if (q == 0 && bb < 4){
                        float4 v4 = make_float4(ob0, ob1, ob2, s);
                        *(float4*)(out + (size_t)(b0+bb)*TT + (t - 3)) = v4;
                    }
                }
            }
            __syncthreads();
        }
    }
}

extern "C" void kernel_launch(void* const* d_in, const int* in_sizes, int n_in,
                              void* d_out, int out_size, void* d_ws, size_t ws_size,
                              hipStream_t stream)
{
    (void)in_sizes; (void)n_in; (void)d_ws; (void)ws_size; (void)out_size;
    const float* x     = (const float*)d_in[0];
    const float* w_ih1 = (const float*)d_in[1];
    const float* w_hh1 = (const float*)d_in[2];
    const float* b1    = (const float*)d_in[3];
    const float* w_ih2 = (const float*)d_in[4];
    const float* w_hh2 = (const float*)d_in[5];
    const float* b2    = (const float*)d_in[6];
    const float* w_ih3 = (const float*)d_in[7];
    const float* w_hh3 = (const float*)d_in[8];
    const float* b3    = (const float*)d_in[9];
    const float* fc1_w = (const float*)d_in[10];
    const float* fc1_b = (const float*)d_in[11];
    const float* fc2_w = (const float*)d_in[12];
    const float* fc2_b = (const float*)d_in[13];

    lstm3_kwave<<<dim3(256), dim3(256), 0, stream>>>(
        x, w_ih1, w_hh1, b1, w_ih2, w_hh2, b2, w_ih3, w_hh3, b3,
        fc1_w, fc1_b, fc2_w, fc2_b, (float*)d_out);
}